// Round 2
// baseline (566.349 us; speedup 1.0000x reference)
//
#include <hip/hip_runtime.h>

#define B_   2
#define N_   2048
#define C_   1024
#define H_   16
#define D_   64
#define HID_ 4096
#define M_   (B_ * N_)   // 4096 rows

typedef __attribute__((ext_vector_type(8))) short bf16x8;  // 8 bf16 = 4 VGPRs
typedef __attribute__((ext_vector_type(4))) float f32x4;

__device__ __forceinline__ unsigned short f2bf(float f) {
  unsigned int u = __builtin_bit_cast(unsigned int, f);
  u += 0x7fffu + ((u >> 16) & 1u);   // RNE
  return (unsigned short)(u >> 16);
}

// async global->LDS, 16B per lane; LDS dest = wave-uniform base + lane*16
__device__ __forceinline__ void gl2lds16(const void* g, void* l) {
  __builtin_amdgcn_global_load_lds(
      (const __attribute__((address_space(1))) unsigned int*)g,
      (__attribute__((address_space(3))) unsigned int*)l, 16, 0, 0);
}

// ---------------- LayerNorm (fp32 in -> bf16 out), one block per row ----------------
__global__ __launch_bounds__(256) void ln_kernel(const float* __restrict__ x,
                                                 const float* __restrict__ g,
                                                 const float* __restrict__ bta,
                                                 unsigned short* __restrict__ out) {
  int row = blockIdx.x;
  int tid = threadIdx.x;
  const float4 v = *(const float4*)(x + (size_t)row * C_ + tid * 4);
  float s1 = v.x + v.y + v.z + v.w;
  float s2 = v.x * v.x + v.y * v.y + v.z * v.z + v.w * v.w;
#pragma unroll
  for (int m = 1; m < 64; m <<= 1) { s1 += __shfl_xor(s1, m); s2 += __shfl_xor(s2, m); }
  __shared__ float red[2][4];
  int w = tid >> 6, lane = tid & 63;
  if (lane == 0) { red[0][w] = s1; red[1][w] = s2; }
  __syncthreads();
  s1 = red[0][0] + red[0][1] + red[0][2] + red[0][3];
  s2 = red[1][0] + red[1][1] + red[1][2] + red[1][3];
  float mu  = s1 * (1.0f / C_);
  float var = s2 * (1.0f / C_) - mu * mu;
  float rs  = rsqrtf(var + 1e-5f);
  const float4 gv = *(const float4*)(g + tid * 4);
  const float4 bv = *(const float4*)(bta + tid * 4);
  ushort4 o;
  o.x = f2bf((v.x - mu) * rs * gv.x + bv.x);
  o.y = f2bf((v.y - mu) * rs * gv.y + bv.y);
  o.z = f2bf((v.z - mu) * rs * gv.z + bv.z);
  o.w = f2bf((v.w - mu) * rs * gv.w + bv.w);
  *(ushort4*)(out + (size_t)row * C_ + tid * 4) = o;
}

// ---------------- Weight transpose + fp32->bf16: W[K][N] -> Wt[N][K] ----------------
__global__ __launch_bounds__(256) void wtrans_kernel(const float* __restrict__ W,
                                                     unsigned short* __restrict__ Wt,
                                                     int K, int N) {
  __shared__ float t[32][33];
  int n0 = blockIdx.x * 32, k0 = blockIdx.y * 32;
  int tx = threadIdx.x, ty = threadIdx.y;  // 32 x 8
#pragma unroll
  for (int j = 0; j < 4; j++)
    t[ty + j * 8][tx] = W[(size_t)(k0 + ty + j * 8) * N + n0 + tx];
  __syncthreads();
#pragma unroll
  for (int j = 0; j < 4; j++)
    Wt[(size_t)(n0 + ty + j * 8) * K + k0 + tx] = f2bf(t[tx][ty + j * 8]);
}

// ---------------- bf16 MFMA GEMM: C[M][N] = A[M][K] @ W[K][N]  (Wt = W^T) -----------
// global_load_lds staging, XOR-swizzled LDS (no padding allowed with the DMA):
//   physical chunk = logical chunk ^ (row & 7).  Fragment rows all have
//   row&7 == r&7, so read-side swizzle is lane-constant across mt/nt tiles.
// MODE 0: scatter to q(*0.125)/k/v bf16 [B,H,N,D]
// MODE 1: outf = acc + bias + resid (fp32)
// MODE 2: outb0 = bf16(gelu_exact(acc + bias))
template <int MODE>
__global__ __launch_bounds__(256) void gemm_kernel(
    const unsigned short* __restrict__ A,    // [M][K] bf16
    const unsigned short* __restrict__ Wt,   // [N][K] bf16
    const float* __restrict__ bias,
    const float* __restrict__ resid,
    float* __restrict__ outf,
    unsigned short* __restrict__ outb0,
    unsigned short* __restrict__ outb1,
    unsigned short* __restrict__ outb2,
    int M, int N, int K) {
  __shared__ __align__(16) unsigned short As[128][64];
  __shared__ __align__(16) unsigned short Bs[128][64];
  int tid = threadIdx.x;
  int w = tid >> 6, lane = tid & 63, r = lane & 15, quad = lane >> 4;
  int wr = w >> 1, wc = w & 1;
  int bM = blockIdx.y * 128, bN = blockIdx.x * 128;

  // staging map: round p covers rows p*32..p*32+31; wave w stages rows w*8..w*8+7
  int srow   = (w << 3) + (lane >> 3);                  // row within round
  int schunk = (lane & 7) ^ ((lane >> 3) & 7);          // swizzled source chunk
  const unsigned short* aP = A  + (size_t)(bM + srow) * K + schunk * 8;
  const unsigned short* bP = Wt + (size_t)(bN + srow) * K + schunk * 8;

  // read-side physical element offsets (chunk*8), kh=0 -> k 0..31, kh=1 -> k 32..63
  int pc0 = (quad ^ (r & 7)) * 8;
  int pc1 = pc0 ^ 32;

  f32x4 acc[4][4];
#pragma unroll
  for (int i = 0; i < 4; i++)
#pragma unroll
    for (int j = 0; j < 4; j++) acc[i][j] = f32x4{0.f, 0.f, 0.f, 0.f};

  for (int k0 = 0; k0 < K; k0 += 64) {
    __syncthreads();
#pragma unroll
    for (int p = 0; p < 4; p++) {
      gl2lds16(aP + (size_t)(p * 32) * K + k0, &As[p * 32 + (w << 3)][0]);
      gl2lds16(bP + (size_t)(p * 32) * K + k0, &Bs[p * 32 + (w << 3)][0]);
    }
    __syncthreads();
#pragma unroll
    for (int kh = 0; kh < 2; kh++) {
      int pc = kh ? pc1 : pc0;
      bf16x8 af[4], bfr[4];
#pragma unroll
      for (int mt = 0; mt < 4; mt++)
        af[mt] = *(const bf16x8*)&As[wr * 64 + mt * 16 + r][pc];
#pragma unroll
      for (int nt = 0; nt < 4; nt++)
        bfr[nt] = *(const bf16x8*)&Bs[wc * 64 + nt * 16 + r][pc];
#pragma unroll
      for (int mt = 0; mt < 4; mt++)
#pragma unroll
        for (int nt = 0; nt < 4; nt++)
          acc[mt][nt] = __builtin_amdgcn_mfma_f32_16x16x32_bf16(af[mt], bfr[nt], acc[mt][nt], 0, 0, 0);
    }
  }

  // Epilogue. D layout: row = quad*4+i, col = r (within 16x16 tile)
#pragma unroll
  for (int mt = 0; mt < 4; mt++) {
#pragma unroll
    for (int nt = 0; nt < 4; nt++) {
#pragma unroll
      for (int i = 0; i < 4; i++) {
        int gm = bM + wr * 64 + mt * 16 + quad * 4 + i;
        int gn = bN + wc * 64 + nt * 16 + r;
        float val = acc[mt][nt][i];
        if (MODE == 0) {
          int s = gn >> 10, c = gn & 1023;
          int hh = c >> 6, d = c & 63;
          int b = gm >> 11, n = gm & 2047;
          size_t di = ((size_t)(b * H_ + hh) * N_ + n) * D_ + d;
          unsigned short bvv = f2bf(s == 0 ? val * 0.125f : val);
          (s == 0 ? outb0 : (s == 1 ? outb1 : outb2))[di] = bvv;
        } else if (MODE == 1) {
          outf[(size_t)gm * N + gn] = val + bias[gn] + resid[(size_t)gm * N + gn];
        } else {
          float t = val + bias[gn];
          float gl = 0.5f * t * (1.0f + erff(t * 0.70710678118f));
          outb0[(size_t)gm * N + gn] = f2bf(gl);
        }
      }
    }
  }
}

// ---------------- Flash attention: q pre-scaled by 1/8; bf16 in, bf16 out ----------
// grid = (B*H) * (N/64); block 256 = 4 waves; wave handles 16 q-rows.
// LDS pitch 138 elements (69 dwords, 69 % 32 = 5, odd stride -> <=2-way banks).
#define VP 138
__global__ __launch_bounds__(256) void attn_kernel(const unsigned short* __restrict__ qb,
                                                   const unsigned short* __restrict__ kb,
                                                   const unsigned short* __restrict__ vb,
                                                   unsigned short* __restrict__ ob) {
  __shared__ __align__(16) unsigned short Vt[64][VP];      // V^T: [d][key]
  __shared__ __align__(16) unsigned short Pl[4][16][VP];   // per-wave P staging
  int tid = threadIdx.x;
  int w = tid >> 6, lane = tid & 63, r = lane & 15, quad = lane >> 4;
  int bh = blockIdx.x >> 5, qt = blockIdx.x & 31;
  const unsigned short* qh = qb + (size_t)bh * N_ * D_;
  const unsigned short* kh = kb + (size_t)bh * N_ * D_;
  const unsigned short* vh = vb + (size_t)bh * N_ * D_;

  // Q fragments (A-layout): row = qt*64 + w*16 + r, k = ks*32 + quad*8 + j
  bf16x8 qf[2];
#pragma unroll
  for (int ks = 0; ks < 2; ks++)
    qf[ks] = *(const bf16x8*)(qh + (size_t)(qt * 64 + w * 16 + r) * D_ + ks * 32 + quad * 8);

  float mst[4], lst[4];
  f32x4 oacc[4];
#pragma unroll
  for (int i = 0; i < 4; i++) { mst[i] = -1e30f; lst[i] = 0.f; }
#pragma unroll
  for (int nt = 0; nt < 4; nt++) oacc[nt] = f32x4{0.f, 0.f, 0.f, 0.f};

  int dg = tid & 15;  // d-group for V staging (16 lanes cover one key row: coalesced)

  for (int t = 0; t < 16; t++) {
    __syncthreads();  // protect Vt from previous-iteration readers
    // stage V transposed, b32 key-pair packed writes (2-way banks at pitch 138)
#pragma unroll
    for (int p = 0; p < 4; p++) {
      int kp = p * 16 + (tid >> 4);
      const unsigned short* vp0 = vh + (size_t)(t * 128 + kp * 2) * D_ + dg * 4;
      uint2 a = *(const uint2*)vp0;
      uint2 b = *(const uint2*)(vp0 + D_);
      unsigned int w0 = (a.x & 0xffffu) | (b.x << 16);
      unsigned int w1 = (a.x >> 16)     | (b.x & 0xffff0000u);
      unsigned int w2 = (a.y & 0xffffu) | (b.y << 16);
      unsigned int w3 = (a.y >> 16)     | (b.y & 0xffff0000u);
      *(unsigned int*)&Vt[dg * 4 + 0][kp * 2] = w0;
      *(unsigned int*)&Vt[dg * 4 + 1][kp * 2] = w1;
      *(unsigned int*)&Vt[dg * 4 + 2][kp * 2] = w2;
      *(unsigned int*)&Vt[dg * 4 + 3][kp * 2] = w3;
    }
    __syncthreads();

    // S = Q K^T (K fragments straight from global, contiguous 16B)
    f32x4 sacc[8];
#pragma unroll
    for (int nt = 0; nt < 8; nt++) sacc[nt] = f32x4{0.f, 0.f, 0.f, 0.f};
#pragma unroll
    for (int ks = 0; ks < 2; ks++) {
#pragma unroll
      for (int nt = 0; nt < 8; nt++) {
        bf16x8 kf = *(const bf16x8*)(kh + (size_t)(t * 128 + nt * 16 + r) * D_ + ks * 32 + quad * 8);
        sacc[nt] = __builtin_amdgcn_mfma_f32_16x16x32_bf16(qf[ks], kf, sacc[nt], 0, 0, 0);
      }
    }

    // online softmax; each quad's 4 rows reduce across the 16 r-lanes
#pragma unroll
    for (int i = 0; i < 4; i++) {
      float tm = sacc[0][i];
#pragma unroll
      for (int nt = 1; nt < 8; nt++) tm = fmaxf(tm, sacc[nt][i]);
#pragma unroll
      for (int m = 1; m < 16; m <<= 1) tm = fmaxf(tm, __shfl_xor(tm, m));
      float mnew  = fmaxf(mst[i], tm);
      float alpha = __expf(mst[i] - mnew);
      mst[i] = mnew;
      float rs = 0.f;
#pragma unroll
      for (int nt = 0; nt < 8; nt++) {
        float p = __expf(sacc[nt][i] - mnew);
        sacc[nt][i] = p;
        rs += p;
      }
#pragma unroll
      for (int m = 1; m < 16; m <<= 1) rs += __shfl_xor(rs, m);
      lst[i] = lst[i] * alpha + rs;
#pragma unroll
      for (int nt = 0; nt < 4; nt++) oacc[nt][i] *= alpha;
    }

    // P: C-layout regs -> LDS -> A-layout (wave-private; DS ops in-order per wave)
#pragma unroll
    for (int nt = 0; nt < 8; nt++)
#pragma unroll
      for (int i = 0; i < 4; i++)
        Pl[w][quad * 4 + i][nt * 16 + r] = f2bf(sacc[nt][i]);

    // O += P @ V
#pragma unroll
    for (int ks = 0; ks < 4; ks++) {
      bf16x8 pf = *(const bf16x8*)&Pl[w][r][ks * 32 + quad * 8];
#pragma unroll
      for (int nt = 0; nt < 4; nt++) {
        bf16x8 vf = *(const bf16x8*)&Vt[nt * 16 + r][ks * 32 + quad * 8];
        oacc[nt] = __builtin_amdgcn_mfma_f32_16x16x32_bf16(pf, vf, oacc[nt], 0, 0, 0);
      }
    }
  }

  // epilogue: o[b][n][h*64+d] bf16
  int bb = bh >> 4, hh = bh & 15;
#pragma unroll
  for (int nt = 0; nt < 4; nt++)
#pragma unroll
    for (int i = 0; i < 4; i++) {
      int row = qt * 64 + w * 16 + quad * 4 + i;
      int d = nt * 16 + r;
      float v = oacc[nt][i] / lst[i];
      ob[((size_t)bb * N_ + row) * C_ + hh * D_ + d] = f2bf(v);
    }
}

// ------------------------------------ launch ---------------------------------------
extern "C" void kernel_launch(void* const* d_in, const int* in_sizes, int n_in,
                              void* d_out, int out_size, void* d_ws, size_t ws_size,
                              hipStream_t stream) {
  const float* x     = (const float*)d_in[0];
  const float* ln1g  = (const float*)d_in[1];
  const float* ln1b  = (const float*)d_in[2];
  const float* wqkv  = (const float*)d_in[3];   // [1024][3072]
  const float* wproj = (const float*)d_in[4];   // [1024][1024]
  const float* bproj = (const float*)d_in[5];
  const float* ln2g  = (const float*)d_in[6];
  const float* ln2b  = (const float*)d_in[7];
  const float* wfc1  = (const float*)d_in[8];   // [1024][4096]
  const float* bfc1  = (const float*)d_in[9];
  const float* wfc2  = (const float*)d_in[10];  // [4096][1024]
  const float* bfc2  = (const float*)d_in[11];
  float* out = (float*)d_out;

  const size_t MB = 1u << 20;
  if (ws_size < 88 * MB) return;  // layout below needs 88 MB
  char* w = (char*)d_ws;
  unsigned short* xn    = (unsigned short*)(w + 0 * MB);   // 8 MB
  unsigned short* qbuf  = (unsigned short*)(w + 8 * MB);   // 8 MB
  unsigned short* kbuf  = (unsigned short*)(w + 16 * MB);  // 8 MB
  unsigned short* vbuf  = (unsigned short*)(w + 24 * MB);  // 8 MB
  unsigned short* hbuf  = (unsigned short*)(w + 0 * MB);   // 32 MB, aliases xn/q/k/v (dead)
  unsigned short* obuf  = (unsigned short*)(w + 32 * MB);  // 8 MB
  float*          x2    = (float*)         (w + 40 * MB);  // 16 MB
  unsigned short* xn2   = (unsigned short*)(w + 56 * MB);  // 8 MB
  unsigned short* wqkvt = (unsigned short*)(w + 64 * MB);  // 6 MB
  unsigned short* wprjt = (unsigned short*)(w + 70 * MB);  // 2 MB
  unsigned short* wfc1t = (unsigned short*)(w + 72 * MB);  // 8 MB
  unsigned short* wfc2t = (unsigned short*)(w + 80 * MB);  // 8 MB

  dim3 tb(32, 8);
  ln_kernel<<<M_, 256, 0, stream>>>(x, ln1g, ln1b, xn);
  wtrans_kernel<<<dim3(3 * C_ / 32, C_ / 32), tb, 0, stream>>>(wqkv, wqkvt, C_, 3 * C_);
  wtrans_kernel<<<dim3(C_ / 32, C_ / 32), tb, 0, stream>>>(wproj, wprjt, C_, C_);
  wtrans_kernel<<<dim3(HID_ / 32, C_ / 32), tb, 0, stream>>>(wfc1, wfc1t, C_, HID_);
  wtrans_kernel<<<dim3(C_ / 32, HID_ / 32), tb, 0, stream>>>(wfc2, wfc2t, HID_, C_);

  gemm_kernel<0><<<dim3(3 * C_ / 128, M_ / 128), 256, 0, stream>>>(
      xn, wqkvt, nullptr, nullptr, nullptr, qbuf, kbuf, vbuf, M_, 3 * C_, C_);
  attn_kernel<<<B_ * H_ * (N_ / 64), 256, 0, stream>>>(qbuf, kbuf, vbuf, obuf);
  gemm_kernel<1><<<dim3(C_ / 128, M_ / 128), 256, 0, stream>>>(
      obuf, wprjt, bproj, x, x2, nullptr, nullptr, nullptr, M_, C_, C_);
  ln_kernel<<<M_, 256, 0, stream>>>(x2, ln2g, ln2b, xn2);
  gemm_kernel<2><<<dim3(HID_ / 128, M_ / 128), 256, 0, stream>>>(
      xn2, wfc1t, bfc1, nullptr, nullptr, hbuf, nullptr, nullptr, M_, HID_, C_);
  gemm_kernel<1><<<dim3(C_ / 128, M_ / 128), 256, 0, stream>>>(
      hbuf, wfc2t, bfc2, x2, out, nullptr, nullptr, nullptr, M_, C_, HID_);
}

// Round 3
// 385.091 us; speedup vs baseline: 1.4707x; 1.4707x over previous
//
#include <hip/hip_runtime.h>

#define B_   2
#define N_   2048
#define C_   1024
#define H_   16
#define D_   64
#define HID_ 4096
#define M_   (B_ * N_)   // 4096 rows

typedef __attribute__((ext_vector_type(8))) short bf16x8;  // 8 bf16 = 4 VGPRs
typedef __attribute__((ext_vector_type(4))) short short4v; // 4 bf16 = 2 VGPRs
typedef __attribute__((ext_vector_type(4))) float f32x4;

__device__ __forceinline__ unsigned short f2bf(float f) {
  unsigned int u = __builtin_bit_cast(unsigned int, f);
  u += 0x7fffu + ((u >> 16) & 1u);   // RNE
  return (unsigned short)(u >> 16);
}

// async global->LDS, 16B per lane; LDS dest = wave-uniform base + lane*16
__device__ __forceinline__ void gl2lds16(const void* g, void* l) {
  __builtin_amdgcn_global_load_lds(
      (const __attribute__((address_space(1))) unsigned int*)g,
      (__attribute__((address_space(3))) unsigned int*)l, 16, 0, 0);
}

// ---------------- LayerNorm (fp32 in -> bf16 out), one WAVE per row ----------------
__global__ __launch_bounds__(256) void ln_kernel(const float* __restrict__ x,
                                                 const float* __restrict__ g,
                                                 const float* __restrict__ bta,
                                                 unsigned short* __restrict__ out) {
  int row  = blockIdx.x * 4 + (threadIdx.x >> 6);
  int lane = threadIdx.x & 63;
  const float* xr = x + (size_t)row * C_;
  float4 v[4];
  float s1 = 0.f, s2 = 0.f;
#pragma unroll
  for (int j = 0; j < 4; j++) {
    v[j] = *(const float4*)(xr + j * 256 + lane * 4);
    s1 += v[j].x + v[j].y + v[j].z + v[j].w;
    s2 += v[j].x * v[j].x + v[j].y * v[j].y + v[j].z * v[j].z + v[j].w * v[j].w;
  }
#pragma unroll
  for (int m = 1; m < 64; m <<= 1) { s1 += __shfl_xor(s1, m); s2 += __shfl_xor(s2, m); }
  float mu  = s1 * (1.0f / C_);
  float var = s2 * (1.0f / C_) - mu * mu;
  float rs  = rsqrtf(var + 1e-5f);
#pragma unroll
  for (int j = 0; j < 4; j++) {
    const float4 gv = *(const float4*)(g + j * 256 + lane * 4);
    const float4 bv = *(const float4*)(bta + j * 256 + lane * 4);
    ushort4 o;
    o.x = f2bf((v[j].x - mu) * rs * gv.x + bv.x);
    o.y = f2bf((v[j].y - mu) * rs * gv.y + bv.y);
    o.z = f2bf((v[j].z - mu) * rs * gv.z + bv.z);
    o.w = f2bf((v[j].w - mu) * rs * gv.w + bv.w);
    *(ushort4*)(out + (size_t)row * C_ + j * 256 + lane * 4) = o;
  }
}

// ---------------- Weight transpose + fp32->bf16: W[K][N] -> Wt[N][K] ----------------
__global__ __launch_bounds__(256) void wtrans_kernel(const float* __restrict__ W,
                                                     unsigned short* __restrict__ Wt,
                                                     int K, int N) {
  __shared__ float t[32][33];
  int n0 = blockIdx.x * 32, k0 = blockIdx.y * 32;
  int tx = threadIdx.x, ty = threadIdx.y;  // 32 x 8
#pragma unroll
  for (int j = 0; j < 4; j++)
    t[ty + j * 8][tx] = W[(size_t)(k0 + ty + j * 8) * N + n0 + tx];
  __syncthreads();
#pragma unroll
  for (int j = 0; j < 4; j++)
    Wt[(size_t)(n0 + ty + j * 8) * K + k0 + tx] = f2bf(t[tx][ty + j * 8]);
}

// ---------------- V transpose per head: v[bh][n][d] -> vt[bh][d][n] (bf16) ----------
__global__ __launch_bounds__(256) void vtrans_kernel(const unsigned short* __restrict__ v,
                                                     unsigned short* __restrict__ vt) {
  __shared__ unsigned short t[32][33];
  int bh = blockIdx.z;
  int n0 = blockIdx.x * 32, d0 = blockIdx.y * 32;
  const unsigned short* src = v + (size_t)bh * N_ * D_;
  unsigned short* dst = vt + (size_t)bh * D_ * N_;
  int tx = threadIdx.x, ty = threadIdx.y;  // 32 x 8
#pragma unroll
  for (int j = 0; j < 4; j++)
    t[ty + j * 8][tx] = src[(size_t)(n0 + ty + j * 8) * D_ + d0 + tx];
  __syncthreads();
#pragma unroll
  for (int j = 0; j < 4; j++)
    dst[(size_t)(d0 + ty + j * 8) * N_ + n0 + tx] = t[tx][ty + j * 8];
}

// ---------------- bf16 MFMA GEMM: C[M][N] = A[M][K] @ W[K][N]  (Wt = W^T) -----------
// global_load_lds staging, XOR-swizzled LDS (phys chunk = logical ^ (row&7)).
// BN=128: 4 waves 2x2 (64x64 each).  BN=64: 4 waves stacked (32x64 each).
// MODE 0: scatter to q(*0.125)/k/v bf16 [B,H,N,D]
// MODE 1: outf = acc + bias + resid (fp32)
// MODE 2: outb0 = bf16(gelu_exact(acc + bias))
template <int MODE, int BN>
__global__ __launch_bounds__(256) void gemm_kernel(
    const unsigned short* __restrict__ A,    // [M][K] bf16
    const unsigned short* __restrict__ Wt,   // [N][K] bf16
    const float* __restrict__ bias,
    const float* __restrict__ resid,
    float* __restrict__ outf,
    unsigned short* __restrict__ outb0,
    unsigned short* __restrict__ outb1,
    unsigned short* __restrict__ outb2,
    int M, int N, int K) {
  constexpr int MT = (BN == 128) ? 4 : 2;
  __shared__ __align__(16) short As[128][64];
  __shared__ __align__(16) short Bs[BN][64];
  int tid = threadIdx.x;
  int w = tid >> 6, lane = tid & 63, r = lane & 15, quad = lane >> 4;
  int rowbase = (BN == 128) ? (w >> 1) * 64 : w * 32;
  int colbase = (BN == 128) ? (w & 1) * 64 : 0;
  int bM = blockIdx.y * 128, bN = blockIdx.x * BN;

  // staging map: round p covers rows p*32..p*32+31; wave w stages rows w*8..w*8+7
  int srow   = (w << 3) + (lane >> 3);
  int schunk = (lane & 7) ^ ((lane >> 3) & 7);
  const unsigned short* aP = A  + (size_t)(bM + srow) * K + schunk * 8;
  const unsigned short* bP = Wt + (size_t)(bN + srow) * K + schunk * 8;

  int pc0 = (quad ^ (r & 7)) * 8;

  f32x4 acc[MT][4];
#pragma unroll
  for (int i = 0; i < MT; i++)
#pragma unroll
    for (int j = 0; j < 4; j++) acc[i][j] = f32x4{0.f, 0.f, 0.f, 0.f};

  for (int k0 = 0; k0 < K; k0 += 64) {
    __syncthreads();
#pragma unroll
    for (int p = 0; p < 4; p++)
      gl2lds16(aP + (size_t)(p * 32) * K + k0, &As[p * 32 + (w << 3)][0]);
#pragma unroll
    for (int p = 0; p < BN / 32; p++)
      gl2lds16(bP + (size_t)(p * 32) * K + k0, &Bs[p * 32 + (w << 3)][0]);
    __syncthreads();
#pragma unroll
    for (int kh = 0; kh < 2; kh++) {
      int pc = pc0 ^ (kh * 32);
      bf16x8 af[MT], bfr[4];
#pragma unroll
      for (int mt = 0; mt < MT; mt++)
        af[mt] = *(const bf16x8*)&As[rowbase + mt * 16 + r][pc];
#pragma unroll
      for (int nt = 0; nt < 4; nt++)
        bfr[nt] = *(const bf16x8*)&Bs[colbase + nt * 16 + r][pc];
#pragma unroll
      for (int mt = 0; mt < MT; mt++)
#pragma unroll
        for (int nt = 0; nt < 4; nt++)
          acc[mt][nt] = __builtin_amdgcn_mfma_f32_16x16x32_bf16(af[mt], bfr[nt], acc[mt][nt], 0, 0, 0);
    }
  }

  // Epilogue. D layout: row = quad*4+i, col = r (within 16x16 tile)
#pragma unroll
  for (int mt = 0; mt < MT; mt++) {
#pragma unroll
    for (int nt = 0; nt < 4; nt++) {
#pragma unroll
      for (int i = 0; i < 4; i++) {
        int gm = bM + rowbase + mt * 16 + quad * 4 + i;
        int gn = bN + colbase + nt * 16 + r;
        float val = acc[mt][nt][i];
        if (MODE == 0) {
          int s = gn >> 10, c = gn & 1023;
          int hh = c >> 6, d = c & 63;
          int b = gm >> 11, n = gm & 2047;
          size_t di = ((size_t)(b * H_ + hh) * N_ + n) * D_ + d;
          unsigned short bvv = f2bf(s == 0 ? val * 0.125f : val);
          (s == 0 ? outb0 : (s == 1 ? outb1 : outb2))[di] = bvv;
        } else if (MODE == 1) {
          outf[(size_t)gm * N + gn] = val + bias[gn] + resid[(size_t)gm * N + gn];
        } else {
          float t = val + bias[gn];
          float gl = 0.5f * t * (1.0f + erff(t * 0.70710678118f));
          outb0[(size_t)gm * N + gn] = f2bf(gl);
        }
      }
    }
  }
}

// ---------------- Flash attention (S^T formulation), q pre-scaled by 1/8 ------------
// grid = (B*H) * (N/128); block 256 = 4 waves; wave handles 32 q-rows.
// K-tile and V^T-tile staged via global_load_lds with XOR swizzle; P reuses Ks.
__global__ __launch_bounds__(256) void attn_kernel(const unsigned short* __restrict__ qb,
                                                   const unsigned short* __restrict__ kb,
                                                   const unsigned short* __restrict__ vtb,
                                                   unsigned short* __restrict__ ob) {
  __shared__ __align__(16) short Ks[128][64];   // 16 KB; reused as Pl[4][16][128]
  __shared__ __align__(16) short Vts[64][128];  // 16 KB  (V^T: [d][key])
  int tid = threadIdx.x;
  int w = tid >> 6, lane = tid & 63, r = lane & 15, quad = lane >> 4;
  int bh = blockIdx.x >> 4, qt = blockIdx.x & 15;
  const unsigned short* qh  = qb  + (size_t)bh * N_ * D_;
  const unsigned short* kh  = kb  + (size_t)bh * N_ * D_;
  const unsigned short* vth = vtb + (size_t)bh * D_ * N_;

  // Q fragments (B-operand): row = qt*128 + w*32 + mt*16 + r, k = ks*32 + quad*8 + j
  bf16x8 qf[2][2];
#pragma unroll
  for (int mt = 0; mt < 2; mt++)
#pragma unroll
    for (int ks = 0; ks < 2; ks++)
      qf[mt][ks] = *(const bf16x8*)(qh + (size_t)(qt * 128 + w * 32 + mt * 16 + r) * D_ + ks * 32 + quad * 8);

  float mst[2] = {-1e30f, -1e30f}, lst[2] = {0.f, 0.f};
  f32x4 oacc[2][4];
#pragma unroll
  for (int mt = 0; mt < 2; mt++)
#pragma unroll
    for (int nt = 0; nt < 4; nt++) oacc[mt][nt] = f32x4{0.f, 0.f, 0.f, 0.f};

  // staging maps
  int krow   = (w << 3) + (lane >> 3);                  // K: 8 rows/wave/round
  int kchunk = (lane & 7) ^ ((lane >> 3) & 7);
  const unsigned short* kP = kh + (size_t)krow * D_ + kchunk * 8;
  int vrow   = (w << 2) + (lane >> 4);                  // Vt: 4 rows/wave/round
  int vchunk = (lane & 15) ^ (vrow & 7);
  const unsigned short* vP = vth + (size_t)vrow * N_ + vchunk * 8;

  short* Plw = &Ks[0][0] + w * 2048;  // wave-private 16x128 P tile (overlays Ks)
  int swz = (r & 7);

  for (int t = 0; t < 16; t++) {
    __syncthreads();  // all waves done with Vts/Pl(Ks) from prev iter
#pragma unroll
    for (int p = 0; p < 4; p++)
      gl2lds16(kP + (size_t)(t * 128 + p * 32) * D_, &Ks[p * 32 + (w << 3)][0]);
#pragma unroll
    for (int p = 0; p < 4; p++)
      gl2lds16(vP + (size_t)(p * 16) * N_ + t * 128, &Vts[p * 16 + (w << 2)][0]);
    __syncthreads();  // staged data visible

    // S^T = K Q^T : D[key=quad*4+i][qrow=r]
    f32x4 sacc[2][8];
#pragma unroll
    for (int mt = 0; mt < 2; mt++)
#pragma unroll
      for (int nt = 0; nt < 8; nt++) sacc[mt][nt] = f32x4{0.f, 0.f, 0.f, 0.f};
#pragma unroll
    for (int ks = 0; ks < 2; ks++) {
#pragma unroll
      for (int nt = 0; nt < 8; nt++) {
        bf16x8 kfr = *(const bf16x8*)&Ks[nt * 16 + r][((ks * 4 + quad) ^ swz) * 8];
#pragma unroll
        for (int mt = 0; mt < 2; mt++)
          sacc[mt][nt] = __builtin_amdgcn_mfma_f32_16x16x32_bf16(kfr, qf[mt][ks], sacc[mt][nt], 0, 0, 0);
      }
    }

    // online softmax per q-row (= column r of S^T); reduce over regs + quads
    float alpha[2];
#pragma unroll
    for (int mt = 0; mt < 2; mt++) {
      float tm = -1e30f;
#pragma unroll
      for (int nt = 0; nt < 8; nt++)
#pragma unroll
        for (int i = 0; i < 4; i++) tm = fmaxf(tm, sacc[mt][nt][i]);
      tm = fmaxf(tm, __shfl_xor(tm, 16));
      tm = fmaxf(tm, __shfl_xor(tm, 32));
      float mnew = fmaxf(mst[mt], tm);
      alpha[mt] = __expf(mst[mt] - mnew);
      mst[mt] = mnew;
      float rs = 0.f;
#pragma unroll
      for (int nt = 0; nt < 8; nt++)
#pragma unroll
        for (int i = 0; i < 4; i++) {
          float p = __expf(sacc[mt][nt][i] - mnew);
          sacc[mt][nt][i] = p;
          rs += p;
        }
      rs += __shfl_xor(rs, 16);
      rs += __shfl_xor(rs, 32);
      lst[mt] = lst[mt] * alpha[mt] + rs;
      // rescale O rows (row = quad*4+i needs alpha of q-row quad*4+i)
#pragma unroll
      for (int i = 0; i < 4; i++) {
        float av = __shfl(alpha[mt], (lane & 48) | (quad * 4 + i));
#pragma unroll
        for (int nt = 0; nt < 4; nt++) oacc[mt][nt][i] *= av;
      }
    }

    __syncthreads();  // all waves done reading Ks -> reuse as Pl

#pragma unroll
    for (int mt = 0; mt < 2; mt++) {
      // write P[mt]: lane's 4 regs = 4 consecutive keys of q-row r -> one b64
#pragma unroll
      for (int nt = 0; nt < 8; nt++) {
        short4v pk;
        pk[0] = (short)f2bf(sacc[mt][nt][0]);
        pk[1] = (short)f2bf(sacc[mt][nt][1]);
        pk[2] = (short)f2bf(sacc[mt][nt][2]);
        pk[3] = (short)f2bf(sacc[mt][nt][3]);
        *(short4v*)&Plw[r * 128 + (((nt * 2 + (quad >> 1)) ^ swz) * 8) + (quad & 1) * 4] = pk;
      }
      asm volatile("" ::: "memory");  // keep reads after writes (wave-private region)
      // O += P V : A = P rows (qrow=r), B = V^T rows (d = nt2*16+r)
#pragma unroll
      for (int ks = 0; ks < 4; ks++) {
        bf16x8 pfr = *(const bf16x8*)&Plw[r * 128 + ((ks * 4 + quad) ^ swz) * 8];
#pragma unroll
        for (int nt2 = 0; nt2 < 4; nt2++) {
          bf16x8 vfr = *(const bf16x8*)&Vts[nt2 * 16 + r][((ks * 4 + quad) ^ swz) * 8];
          oacc[mt][nt2] = __builtin_amdgcn_mfma_f32_16x16x32_bf16(pfr, vfr, oacc[mt][nt2], 0, 0, 0);
        }
      }
      asm volatile("" ::: "memory");  // keep mt=1 writes after mt=0 reads
    }
  }

  // epilogue: o[b][n][h*64+d] bf16;  O C-layout row=quad*4+i, col=r
  int bb = bh >> 4, hh = bh & 15;
#pragma unroll
  for (int mt = 0; mt < 2; mt++) {
#pragma unroll
    for (int i = 0; i < 4; i++) {
      float li = __shfl(lst[mt], (lane & 48) | (quad * 4 + i));
      float inv = 1.0f / li;
      int row = qt * 128 + w * 32 + mt * 16 + quad * 4 + i;
#pragma unroll
      for (int nt2 = 0; nt2 < 4; nt2++) {
        int d = nt2 * 16 + r;
        ob[((size_t)bb * N_ + row) * C_ + hh * D_ + d] = f2bf(oacc[mt][nt2][i] * inv);
      }
    }
  }
}

// ------------------------------------ launch ---------------------------------------
extern "C" void kernel_launch(void* const* d_in, const int* in_sizes, int n_in,
                              void* d_out, int out_size, void* d_ws, size_t ws_size,
                              hipStream_t stream) {
  const float* x     = (const float*)d_in[0];
  const float* ln1g  = (const float*)d_in[1];
  const float* ln1b  = (const float*)d_in[2];
  const float* wqkv  = (const float*)d_in[3];   // [1024][3072]
  const float* wproj = (const float*)d_in[4];   // [1024][1024]
  const float* bproj = (const float*)d_in[5];
  const float* ln2g  = (const float*)d_in[6];
  const float* ln2b  = (const float*)d_in[7];
  const float* wfc1  = (const float*)d_in[8];   // [1024][4096]
  const float* bfc1  = (const float*)d_in[9];
  const float* wfc2  = (const float*)d_in[10];  // [4096][1024]
  const float* bfc2  = (const float*)d_in[11];
  float* out = (float*)d_out;

  const size_t MB = 1u << 20;
  if (ws_size < 88 * MB) return;  // layout below needs 88 MB
  char* w = (char*)d_ws;
  unsigned short* xn    = (unsigned short*)(w + 0 * MB);   // 8 MB
  unsigned short* qbuf  = (unsigned short*)(w + 8 * MB);   // 8 MB
  unsigned short* kbuf  = (unsigned short*)(w + 16 * MB);  // 8 MB
  unsigned short* vbuf  = (unsigned short*)(w + 24 * MB);  // 8 MB
  unsigned short* hbuf  = (unsigned short*)(w + 0 * MB);   // 32 MB, aliases xn/q/k/v (dead by fc1)
  unsigned short* obuf  = (unsigned short*)(w + 32 * MB);  // 8 MB
  float*          x2    = (float*)         (w + 40 * MB);  // 16 MB
  unsigned short* xn2   = (unsigned short*)(w + 56 * MB);  // 8 MB
  unsigned short* vtb   = (unsigned short*)(w + 56 * MB);  // 8 MB, dead before xn2 is written
  unsigned short* wqkvt = (unsigned short*)(w + 64 * MB);  // 6 MB
  unsigned short* wprjt = (unsigned short*)(w + 70 * MB);  // 2 MB
  unsigned short* wfc1t = (unsigned short*)(w + 72 * MB);  // 8 MB
  unsigned short* wfc2t = (unsigned short*)(w + 80 * MB);  // 8 MB

  dim3 tb(32, 8);
  ln_kernel<<<M_ / 4, 256, 0, stream>>>(x, ln1g, ln1b, xn);
  wtrans_kernel<<<dim3(3 * C_ / 32, C_ / 32), tb, 0, stream>>>(wqkv, wqkvt, C_, 3 * C_);
  wtrans_kernel<<<dim3(C_ / 32, C_ / 32), tb, 0, stream>>>(wproj, wprjt, C_, C_);
  wtrans_kernel<<<dim3(HID_ / 32, C_ / 32), tb, 0, stream>>>(wfc1, wfc1t, C_, HID_);
  wtrans_kernel<<<dim3(C_ / 32, HID_ / 32), tb, 0, stream>>>(wfc2, wfc2t, HID_, C_);

  gemm_kernel<0, 128><<<dim3(3 * C_ / 128, M_ / 128), 256, 0, stream>>>(
      xn, wqkvt, nullptr, nullptr, nullptr, qbuf, kbuf, vbuf, M_, 3 * C_, C_);
  vtrans_kernel<<<dim3(N_ / 32, D_ / 32, B_ * H_), tb, 0, stream>>>(vbuf, vtb);
  attn_kernel<<<B_ * H_ * (N_ / 128), 256, 0, stream>>>(qbuf, kbuf, vtb, obuf);
  gemm_kernel<1, 64><<<dim3(C_ / 64, M_ / 128), 256, 0, stream>>>(
      obuf, wprjt, bproj, x, x2, nullptr, nullptr, nullptr, M_, C_, C_);
  ln_kernel<<<M_ / 4, 256, 0, stream>>>(x2, ln2g, ln2b, xn2);
  gemm_kernel<2, 128><<<dim3(HID_ / 128, M_ / 128), 256, 0, stream>>>(
      xn2, wfc1t, bfc1, nullptr, nullptr, hbuf, nullptr, nullptr, M_, HID_, C_);
  gemm_kernel<1, 64><<<dim3(C_ / 64, M_ / 128), 256, 0, stream>>>(
      hbuf, wfc2t, bfc2, x2, out, nullptr, nullptr, nullptr, M_, C_, HID_);
}